// Round 4
// baseline (293.462 us; speedup 1.0000x reference)
//
#include <hip/hip_runtime.h>
#include <hip/hip_fp16.h>
#include <stdint.h>

#define DIM 256
#define KE  768

typedef _Float16 half8 __attribute__((ext_vector_type(8)));
typedef float floatx4 __attribute__((ext_vector_type(4)));

// Workspace layout (bytes) — total 21,288,000 (vs 21,091,328 proven baseline):
//   Xe    : 8192*768 ushort @ 0          (12,582,912)  [xh*64 | xh | xl*2^11]
//   We    : 5376*768 ushort @ 12582912   ( 8,257,536)  [wh*32 | wl*2^11 | wh]
//   wnorm : 5376 float      @ 20840448
//   xnorm : 8192 float      @ 20861952
//   m1    : 24576 u64       @ 20894720   global best (d2<<32)|col per (lvl,row)
//   m2    : 24576 u32       @ 21091328   global 2nd-best d2 bits
//   lists : 3*8192 u32      @ 21189632   flagged row indices per level
//   ctrl  : 16 u32          @ 21287936   [0..2]=wmax bits, [4..6]=counts
#define WS_WE_OFF    12582912
#define WS_WNORM_OFF 20840448
#define WS_XNORM_OFF 20861952
#define WS_M1_OFF    20894720
#define WS_M2_OFF    21091328
#define WS_LISTS_OFF 21189632
#define WS_CTRL_OFF  21287936

// One wave per row: fp32 norm + fp16 hi/lo split into the expanded layouts.
// Pass-1 uses plain segments: Xe[256..512)=xh, We[512..768)=wh.
// Pass-2 pairing: (xh*64)*(wh*32) ; xh*(wl*2^11) ; (xl*2^11)*wh
//   => acc = 2^11 * (xh*wh + xh*wl + xl*wh)  (pow2 scales exact in fp16).
__global__ __launch_bounds__(256) void conv_kernel(
    const float* __restrict__ x, const float* __restrict__ w1,
    const float* __restrict__ w2, const float* __restrict__ w3,
    ushort* __restrict__ Xe, ushort* __restrict__ We,
    float* __restrict__ wnorm, float* __restrict__ xnorm,
    unsigned* __restrict__ wmaxp) {
  int task = blockIdx.x * 4 + (threadIdx.x >> 6);
  int lane = threadIdx.x & 63;
  const float* src; ushort* dst; float* ndst; int isx; int lvl = 0;
  if (task < 8192) {
    src = x + (size_t)task * DIM; dst = Xe + (size_t)task * KE;
    ndst = xnorm + task; isx = 1;
  } else {
    int wi = task - 8192;
    if (wi < 256)       { src = w1 + (size_t)wi * DIM; lvl = 0; }
    else if (wi < 1280) { src = w2 + (size_t)(wi - 256) * DIM; lvl = 1; }
    else                { src = w3 + (size_t)(wi - 1280) * DIM; lvl = 2; }
    dst = We + (size_t)wi * KE; ndst = wnorm + wi; isx = 0;
  }
  float4 v = *(const float4*)(src + lane * 4);
  float fv[4] = {v.x, v.y, v.z, v.w};
  float s = fv[0]*fv[0] + fv[1]*fv[1] + fv[2]*fv[2] + fv[3]*fv[3];
  #pragma unroll
  for (int o = 32; o > 0; o >>= 1) s += __shfl_xor(s, o);
  if (lane == 0) {
    *ndst = s;
    if (!isx) atomicMax(wmaxp + lvl, __float_as_uint(s));
  }

  float scale = isx ? 64.0f : 32.0f;
  ushort h[4], hs[4], l[4];
  #pragma unroll
  for (int e = 0; e < 4; ++e) {
    __half hh = __float2half(fv[e]);
    float hf = __half2float(hh);
    h[e]  = __half_as_ushort(hh);
    hs[e] = __half_as_ushort(__float2half(hf * scale));
    l[e]  = __half_as_ushort(__float2half((fv[e] - hf) * 2048.0f));
  }
  ushort4 h4 = make_ushort4(h[0], h[1], h[2], h[3]);
  ushort4 s4 = make_ushort4(hs[0], hs[1], hs[2], hs[3]);
  ushort4 l4 = make_ushort4(l[0], l[1], l[2], l[3]);
  if (isx) {  // [xh*64 | xh | xl2]
    *(ushort4*)(dst + lane * 4)        = s4;
    *(ushort4*)(dst + 256 + lane * 4)  = h4;
    *(ushort4*)(dst + 512 + lane * 4)  = l4;
  } else {    // [wh*32 | wl2 | wh]
    *(ushort4*)(dst + lane * 4)        = s4;
    *(ushort4*)(dst + 256 + lane * 4)  = l4;
    *(ushort4*)(dst + 512 + lane * 4)  = h4;
  }
}

__device__ __forceinline__ void min2merge(unsigned long long& p1,
                                          unsigned long long& p2,
                                          unsigned long long o1,
                                          unsigned long long o2) {
  unsigned long long lo = p1 < o1 ? p1 : o1;
  unsigned long long hi = p1 < o1 ? o1 : p1;
  unsigned long long mm = p2 < o2 ? p2 : o2;
  p1 = lo;
  p2 = hi < mm ? hi : mm;
}

// Pass 1: 128x128-tile MFMA GEMM over K=256 (plain hh segments), reducing
// directly into global best-2 per (level,row) via lock-free atomics:
//   old = atomicMin(m1, v); push = (v<old ? old : v); atomicMin(m2, push.d2)
// Every value except the final min is pushed to m2 => m2 = true 2nd best.
__global__ __launch_bounds__(256) void gemm1_kernel(
    const ushort* __restrict__ Xe, const ushort* __restrict__ We,
    const float* __restrict__ xnorm, const float* __restrict__ wnorm,
    unsigned long long* __restrict__ m1, unsigned* __restrict__ m2) {
  __shared__ __align__(16) ushort As[128 * 64];
  __shared__ __align__(16) ushort Bs[128 * 64];
  __shared__ unsigned long long red1[2][128], red2[2][128];

  const int cb = blockIdx.x;
  const int r0 = blockIdx.y * 128;
  const int n0 = cb * 128;
  int level, lbase;
  if (cb < 2)       { level = 0; lbase = 0; }
  else if (cb < 10) { level = 1; lbase = 256; }
  else              { level = 2; lbase = 1280; }

  const int t = threadIdx.x;
  const int w = t >> 6;
  const int lane = t & 63;
  const int ln = lane & 15, q = lane >> 4;
  const int wm = (w >> 1) * 64, wn = (w & 1) * 64;

  floatx4 acc[4][4];
  #pragma unroll
  for (int i = 0; i < 4; ++i)
    #pragma unroll
    for (int j = 0; j < 4; ++j) acc[i][j] = (floatx4)0.0f;

  for (int k0 = 0; k0 < 256; k0 += 64) {
    #pragma unroll
    for (int it = 0; it < 4; ++it) {
      int p = it * 256 + t;
      int m = p >> 3;
      int c = (p & 7) ^ (m & 7);
      const ushort* ga = Xe + (size_t)(r0 + m) * KE + 256 + k0 + c * 8;
      const ushort* gb = We + (size_t)(n0 + m) * KE + 512 + k0 + c * 8;
      int lbc = it * 256 + (t & 192);  // wave-uniform
      __builtin_amdgcn_global_load_lds(
          (const __attribute__((address_space(1))) void*)ga,
          (__attribute__((address_space(3))) void*)(As + lbc * 8), 16, 0, 0);
      __builtin_amdgcn_global_load_lds(
          (const __attribute__((address_space(1))) void*)gb,
          (__attribute__((address_space(3))) void*)(Bs + lbc * 8), 16, 0, 0);
    }
    __syncthreads();
    #pragma unroll
    for (int s = 0; s < 2; ++s) {
      half8 a[4], b[4];
      #pragma unroll
      for (int mt = 0; mt < 4; ++mt) {
        int m = wm + mt * 16 + ln;
        int pos = m * 8 + ((s * 4 + q) ^ (m & 7));
        a[mt] = *(const half8*)&As[pos * 8];
      }
      #pragma unroll
      for (int nt = 0; nt < 4; ++nt) {
        int n = wn + nt * 16 + ln;
        int pos = n * 8 + ((s * 4 + q) ^ (n & 7));
        b[nt] = *(const half8*)&Bs[pos * 8];
      }
      #pragma unroll
      for (int mt = 0; mt < 4; ++mt)
        #pragma unroll
        for (int nt = 0; nt < 4; ++nt)
          acc[mt][nt] = __builtin_amdgcn_mfma_f32_16x16x32_f16(
              a[mt], b[nt], acc[mt][nt], 0, 0, 0);
    }
    __syncthreads();
  }

  // s1 = xn + wn - 2*acc (acc = xh.wh, fp32-accumulated)
  float wnv[4];
  #pragma unroll
  for (int nt = 0; nt < 4; ++nt) wnv[nt] = wnorm[n0 + wn + nt * 16 + ln];

  #pragma unroll
  for (int mt = 0; mt < 4; ++mt) {
    #pragma unroll
    for (int r = 0; r < 4; ++r) {
      int rowl = wm + mt * 16 + q * 4 + r;
      float xnv = xnorm[r0 + rowl];
      unsigned long long p1 = ~0ull, p2 = ~0ull;
      #pragma unroll
      for (int nt = 0; nt < 4; ++nt) {
        float d2 = fmaxf(xnv + wnv[nt] - 2.0f * acc[mt][nt][r], 0.0f);
        unsigned col = (unsigned)(n0 + wn + nt * 16 + ln - lbase);
        unsigned long long p =
            ((unsigned long long)__float_as_uint(d2) << 32) | col;
        if (p < p1) { p2 = p1; p1 = p; }
        else if (p < p2) { p2 = p; }
      }
      #pragma unroll
      for (int off = 1; off < 16; off <<= 1) {
        unsigned long long o1 = __shfl_xor(p1, off);
        unsigned long long o2 = __shfl_xor(p2, off);
        min2merge(p1, p2, o1, o2);
      }
      if (ln == 0) { red1[w & 1][rowl] = p1; red2[w & 1][rowl] = p2; }
    }
  }
  __syncthreads();
  if (t < 128) {
    unsigned long long a1 = red1[0][t], a2 = red2[0][t];
    min2merge(a1, a2, red1[1][t], red2[1][t]);
    int slot = level * 8192 + r0 + t;
    unsigned long long old = atomicMin(&m1[slot], a1);
    unsigned push = (a1 < old) ? (unsigned)(old >> 32) : (unsigned)(a1 >> 32);
    atomicMin(&m2[slot], push);
    atomicMin(&m2[slot], (unsigned)(a2 >> 32));
  }
}

// Certainty test per (level,row). Certain: m1 already holds the answer.
// Uncertain: set m1 sentinel and append row to the level's list.
// |s1 - d2_true| <= 2*(2^-11 + 2^-11 + eps)*||x||*||w|| per candidate;
// th = 0.0045*sqrt(xn*wmax) + 0.5 covers 2 candidates with margin.
__global__ __launch_bounds__(256) void listgen_kernel(
    unsigned long long* __restrict__ m1, const unsigned* __restrict__ m2,
    const float* __restrict__ xnorm, const unsigned* __restrict__ ctrl,
    unsigned* __restrict__ counts, unsigned* __restrict__ lists) {
  int task = blockIdx.x * 256 + threadIdx.x;
  if (task >= 24576) return;
  int level = task >> 13;
  int row = task & 8191;
  float d1 = __uint_as_float((unsigned)(m1[task] >> 32));
  float d2 = __uint_as_float(m2[task]);
  float th = 0.0045f * sqrtf(xnorm[row] * __uint_as_float(ctrl[level]))
           + 0.5f;
  if (!(d2 - d1 > th)) {
    m1[task] = ~0ull;
    unsigned pos = atomicAdd(counts + level, 1u);
    if (pos < 8192u) lists[level * 8192 + pos] = row;
  }
}

// Pass 2: full-precision hi/lo K=768 GEMM restricted to flagged rows
// (gathered via lists); atomicMin results straight into m1.
__global__ __launch_bounds__(256) void gemm2_kernel(
    const ushort* __restrict__ Xe, const ushort* __restrict__ We,
    const float* __restrict__ xnorm, const float* __restrict__ wnorm,
    const unsigned* __restrict__ lists, const unsigned* __restrict__ counts,
    unsigned long long* __restrict__ m1) {
  const int cb = blockIdx.x;
  int level, lbase;
  if (cb < 2)       { level = 0; lbase = 0; }
  else if (cb < 10) { level = 1; lbase = 256; }
  else              { level = 2; lbase = 1280; }
  const unsigned cnt = counts[level];
  const unsigned r0i = blockIdx.y * 128;
  if (r0i >= cnt) return;
  const unsigned* list = lists + level * 8192;

  __shared__ __align__(16) ushort As[128 * 64];
  __shared__ __align__(16) ushort Bs[128 * 64];
  __shared__ unsigned long long red[2][128];

  const int n0 = cb * 128;
  const int t = threadIdx.x;
  const int w = t >> 6;
  const int lane = t & 63;
  const int ln = lane & 15, q = lane >> 4;
  const int wm = (w >> 1) * 64, wn = (w & 1) * 64;

  unsigned ar[4];
  #pragma unroll
  for (int it = 0; it < 4; ++it) {
    unsigned li = r0i + it * 32 + (t >> 3);
    ar[it] = list[li < cnt ? li : (cnt - 1)] & 8191u;
  }

  floatx4 acc[4][4];
  #pragma unroll
  for (int i = 0; i < 4; ++i)
    #pragma unroll
    for (int j = 0; j < 4; ++j) acc[i][j] = (floatx4)0.0f;

  for (int k0 = 0; k0 < KE; k0 += 64) {
    #pragma unroll
    for (int it = 0; it < 4; ++it) {
      int p = it * 256 + t;
      int m = p >> 3;
      int c = (p & 7) ^ (m & 7);
      const ushort* ga = Xe + (size_t)ar[it] * KE + k0 + c * 8;
      const ushort* gb = We + (size_t)(n0 + m) * KE + k0 + c * 8;
      int lbc = it * 256 + (t & 192);
      __builtin_amdgcn_global_load_lds(
          (const __attribute__((address_space(1))) void*)ga,
          (__attribute__((address_space(3))) void*)(As + lbc * 8), 16, 0, 0);
      __builtin_amdgcn_global_load_lds(
          (const __attribute__((address_space(1))) void*)gb,
          (__attribute__((address_space(3))) void*)(Bs + lbc * 8), 16, 0, 0);
    }
    __syncthreads();
    #pragma unroll
    for (int s = 0; s < 2; ++s) {
      half8 a[4], b[4];
      #pragma unroll
      for (int mt = 0; mt < 4; ++mt) {
        int m = wm + mt * 16 + ln;
        int pos = m * 8 + ((s * 4 + q) ^ (m & 7));
        a[mt] = *(const half8*)&As[pos * 8];
      }
      #pragma unroll
      for (int nt = 0; nt < 4; ++nt) {
        int n = wn + nt * 16 + ln;
        int pos = n * 8 + ((s * 4 + q) ^ (n & 7));
        b[nt] = *(const half8*)&Bs[pos * 8];
      }
      #pragma unroll
      for (int mt = 0; mt < 4; ++mt)
        #pragma unroll
        for (int nt = 0; nt < 4; ++nt)
          acc[mt][nt] = __builtin_amdgcn_mfma_f32_16x16x32_f16(
              a[mt], b[nt], acc[mt][nt], 0, 0, 0);
    }
    __syncthreads();
  }

  // acc = 2^11 * dot. d2 = xn + wn - acc * 2^-10.
  float wnv[4];
  #pragma unroll
  for (int nt = 0; nt < 4; ++nt) wnv[nt] = wnorm[n0 + wn + nt * 16 + ln];

  #pragma unroll
  for (int mt = 0; mt < 4; ++mt) {
    #pragma unroll
    for (int r = 0; r < 4; ++r) {
      int rowl = wm + mt * 16 + q * 4 + r;
      unsigned li = r0i + rowl;
      float xnv = xnorm[list[li < cnt ? li : (cnt - 1)] & 8191u];
      unsigned long long bp = ~0ull;
      #pragma unroll
      for (int nt = 0; nt < 4; ++nt) {
        float d2 = fmaxf(xnv + wnv[nt] - acc[mt][nt][r] * 0.0009765625f, 0.0f);
        unsigned col = (unsigned)(n0 + wn + nt * 16 + ln - lbase);
        unsigned long long p =
            ((unsigned long long)__float_as_uint(d2) << 32) | col;
        bp = (p < bp) ? p : bp;
      }
      #pragma unroll
      for (int off = 1; off < 16; off <<= 1) {
        unsigned long long o = __shfl_xor(bp, off);
        bp = (o < bp) ? o : bp;
      }
      if (ln == 0) red[w & 1][rowl] = bp;
    }
  }
  __syncthreads();
  if (t < 128 && r0i + t < cnt) {
    unsigned long long a = red[0][t], b = red[1][t];
    unsigned long long m = (a < b) ? a : b;
    atomicMin(&m1[level * 8192 + (list[r0i + t] & 8191u)], m);
  }
}

// One wave per (level,row): coords + exact fp32 quantization error.
__global__ __launch_bounds__(256) void finalize_kernel(
    const float* __restrict__ x, const float* __restrict__ w1,
    const float* __restrict__ w2, const float* __restrict__ w3,
    const unsigned long long* __restrict__ m1, float* __restrict__ out) {
  int task = blockIdx.x * 4 + (threadIdx.x >> 6);
  int lane = threadIdx.x & 63;
  int level = task >> 13;
  int row = task & 8191;
  const float* w; unsigned side;
  if (level == 0)      { w = w1; side = 16; }
  else if (level == 1) { w = w2; side = 32; }
  else                 { w = w3; side = 64; }
  unsigned idx = (unsigned)(m1[task] & 0xFFFFFFFFull);
  if (idx >= side * side) idx = 0;   // defensive: never fault on a bad gather
  float4 xv = *(const float4*)(x + (size_t)row * DIM + lane * 4);
  float4 wv = *(const float4*)(w + (size_t)idx * DIM + lane * 4);
  float dx = xv.x - wv.x, dy = xv.y - wv.y, dz = xv.z - wv.z, dw = xv.w - wv.w;
  float s = dx * dx + dy * dy + dz * dz + dw * dw;
  #pragma unroll
  for (int o = 32; o > 0; o >>= 1) s += __shfl_xor(s, o);
  if (lane == 0) {
    out[level * 16384 + row * 2 + 0] = (float)(idx / side);
    out[level * 16384 + row * 2 + 1] = (float)(idx % side);
    out[49152 + level * 8192 + row] = sqrtf(s);
  }
}

extern "C" void kernel_launch(void* const* d_in, const int* in_sizes, int n_in,
                              void* d_out, int out_size, void* d_ws, size_t ws_size,
                              hipStream_t stream) {
  const float* x  = (const float*)d_in[0];
  const float* w1 = (const float*)d_in[1];
  const float* w2 = (const float*)d_in[2];
  const float* w3 = (const float*)d_in[3];
  ushort* Xe = (ushort*)d_ws;
  ushort* We = (ushort*)((char*)d_ws + WS_WE_OFF);
  float* wnorm = (float*)((char*)d_ws + WS_WNORM_OFF);
  float* xnorm = (float*)((char*)d_ws + WS_XNORM_OFF);
  unsigned long long* m1 = (unsigned long long*)((char*)d_ws + WS_M1_OFF);
  unsigned* m2 = (unsigned*)((char*)d_ws + WS_M2_OFF);
  unsigned* lists = (unsigned*)((char*)d_ws + WS_LISTS_OFF);
  unsigned* ctrl  = (unsigned*)((char*)d_ws + WS_CTRL_OFF);   // wmax[0..2]
  unsigned* counts = ctrl + 4;                                 // counts[4..6]

  hipMemsetAsync(m1, 0xFF, 24576 * 8 + 24576 * 4, stream);  // m1 + m2
  hipMemsetAsync(ctrl, 0, 64, stream);
  conv_kernel<<<3392, 256, 0, stream>>>(x, w1, w2, w3, Xe, We, wnorm, xnorm,
                                        ctrl);
  gemm1_kernel<<<dim3(42, 64), 256, 0, stream>>>(Xe, We, xnorm, wnorm, m1, m2);
  listgen_kernel<<<96, 256, 0, stream>>>(m1, m2, xnorm, ctrl, counts, lists);
  gemm2_kernel<<<dim3(42, 64), 256, 0, stream>>>(Xe, We, xnorm, wnorm, lists,
                                                 counts, m1);
  finalize_kernel<<<6144, 256, 0, stream>>>(x, w1, w2, w3, m1, (float*)d_out);
}

// Round 5
// 162.752 us; speedup vs baseline: 1.8031x; 1.8031x over previous
//
#include <hip/hip_runtime.h>
#include <hip/hip_fp16.h>
#include <stdint.h>

#define DIM 256
#define KE  768
#define NW  5376

typedef _Float16 half8 __attribute__((ext_vector_type(8)));
typedef float floatx4 __attribute__((ext_vector_type(4)));

// Workspace layout (bytes):
//   Xe    : 8192*768 ushort @ 0          (12,582,912)  [xh | xh | xl*2^11]
//   We    : 5376*768 ushort @ 12582912   ( 8,257,536)  [wh | wl*2^11 | wh]
//   wnorm : 5376 float      @ 20840448
//   xnorm : 8192 float      @ 20861952
//   best  : 24576 u64       @ 20894720   (level*8192+row) packed (d2<<32)|idx
#define WS_WE_OFF    12582912
#define WS_WNORM_OFF 20840448
#define WS_XNORM_OFF 20861952
#define WS_BEST_OFF  20894720

// One wave per row: fp32 norm + fp16 hi/lo split into the expanded layouts.
// Also initializes best[] (blocks 0..95) so no separate memset dispatch.
__global__ __launch_bounds__(256) void conv_kernel(
    const float* __restrict__ x, const float* __restrict__ w1,
    const float* __restrict__ w2, const float* __restrict__ w3,
    ushort* __restrict__ Xe, ushort* __restrict__ We,
    float* __restrict__ wnorm, float* __restrict__ xnorm,
    unsigned long long* __restrict__ best) {
  if (blockIdx.x < 96) best[blockIdx.x * 256 + threadIdx.x] = ~0ull;
  int task = blockIdx.x * 4 + (threadIdx.x >> 6);
  int lane = threadIdx.x & 63;
  const float* src; ushort* dst; float* ndst; int isx;
  if (task < 8192) {
    src = x + (size_t)task * DIM; dst = Xe + (size_t)task * KE;
    ndst = xnorm + task; isx = 1;
  } else {
    int wi = task - 8192;
    if (wi < 256)       src = w1 + (size_t)wi * DIM;
    else if (wi < 1280) src = w2 + (size_t)(wi - 256) * DIM;
    else                src = w3 + (size_t)(wi - 1280) * DIM;
    dst = We + (size_t)wi * KE; ndst = wnorm + wi; isx = 0;
  }
  float4 v = *(const float4*)(src + lane * 4);
  float fv[4] = {v.x, v.y, v.z, v.w};
  float s = fv[0]*fv[0] + fv[1]*fv[1] + fv[2]*fv[2] + fv[3]*fv[3];
  #pragma unroll
  for (int o = 32; o > 0; o >>= 1) s += __shfl_xor(s, o);
  if (lane == 0) *ndst = s;

  ushort h[4], l[4];
  #pragma unroll
  for (int e = 0; e < 4; ++e) {
    __half hh = __float2half(fv[e]);
    float hf = __half2float(hh);
    __half ll = __float2half((fv[e] - hf) * 2048.0f);  // scaled lo: no denorms
    h[e] = __half_as_ushort(hh);
    l[e] = __half_as_ushort(ll);
  }
  ushort4 h4 = make_ushort4(h[0], h[1], h[2], h[3]);
  ushort4 l4 = make_ushort4(l[0], l[1], l[2], l[3]);
  if (isx) {  // [xh | xh | xl2]
    *(ushort4*)(dst + lane * 4)        = h4;
    *(ushort4*)(dst + 256 + lane * 4)  = h4;
    *(ushort4*)(dst + 512 + lane * 4)  = l4;
  } else {    // [wh | wl2 | wh]
    *(ushort4*)(dst + lane * 4)        = h4;
    *(ushort4*)(dst + 256 + lane * 4)  = l4;
    *(ushort4*)(dst + 512 + lane * 4)  = h4;
  }
}

// 128x128 tile MFMA GEMM over K=768 with fused per-row argmin.
// LDS trimmed to exactly 32 KB (red[] aliased into As after the K-loop)
// -> 5 blocks/CU instead of 4: more co-resident waves to hide the
// per-K-step barrier/staging drain (the measured latency bottleneck).
// grid.x = 42 col-blocks (2 | 8 | 32 per level), grid.y = 64 row-blocks.
__global__ __launch_bounds__(256) void gemm_kernel(
    const ushort* __restrict__ Xe, const ushort* __restrict__ We,
    const float* __restrict__ xnorm, const float* __restrict__ wnorm,
    unsigned long long* __restrict__ best) {
  __shared__ __align__(16) ushort As[128 * 64];  // 16KB, XOR-swizzled chunks
  __shared__ __align__(16) ushort Bs[128 * 64];
  // red[2][128] u64 (2 KB) aliases As: first written after the K-loop's
  // final __syncthreads(), when no wave reads As anymore.
  unsigned long long (*red)[128] = (unsigned long long (*)[128])As;

  const int cb = blockIdx.x;
  const int r0 = blockIdx.y * 128;
  const int n0 = cb * 128;
  int level, lbase;
  if (cb < 2)       { level = 0; lbase = 0; }
  else if (cb < 10) { level = 1; lbase = 256; }
  else              { level = 2; lbase = 1280; }

  const int t = threadIdx.x;
  const int w = t >> 6;
  const int lane = t & 63;
  const int ln = lane & 15, q = lane >> 4;
  const int wm = (w >> 1) * 64, wn = (w & 1) * 64;

  floatx4 acc[4][4];
  #pragma unroll
  for (int i = 0; i < 4; ++i)
    #pragma unroll
    for (int j = 0; j < 4; ++j) acc[i][j] = (floatx4)0.0f;

  for (int k0 = 0; k0 < KE; k0 += 64) {
    if (k0 == 256) {  // hh phase done: scale so cross terms (pre-scaled 2^11) match
      #pragma unroll
      for (int i = 0; i < 4; ++i)
        #pragma unroll
        for (int j = 0; j < 4; ++j) acc[i][j] *= 2048.0f;
    }
    // Stage A and B tiles: 1024 16B-chunks each; chunk p holds global
    // (row m = p>>3, colchunk c = (p&7)^(m&7)) -> conflict-free frag reads.
    #pragma unroll
    for (int it = 0; it < 4; ++it) {
      int p = it * 256 + t;
      int m = p >> 3;
      int c = (p & 7) ^ (m & 7);
      const ushort* ga = Xe + (size_t)(r0 + m) * KE + k0 + c * 8;
      const ushort* gb = We + (size_t)(n0 + m) * KE + k0 + c * 8;
      int lbase_chunks = it * 256 + (t & 192);  // wave-uniform
      __builtin_amdgcn_global_load_lds(
          (const __attribute__((address_space(1))) void*)ga,
          (__attribute__((address_space(3))) void*)(As + lbase_chunks * 8), 16, 0, 0);
      __builtin_amdgcn_global_load_lds(
          (const __attribute__((address_space(1))) void*)gb,
          (__attribute__((address_space(3))) void*)(Bs + lbase_chunks * 8), 16, 0, 0);
    }
    __syncthreads();
    #pragma unroll
    for (int s = 0; s < 2; ++s) {
      half8 a[4], b[4];
      #pragma unroll
      for (int mt = 0; mt < 4; ++mt) {
        int m = wm + mt * 16 + ln;
        int pos = m * 8 + ((s * 4 + q) ^ (m & 7));
        a[mt] = *(const half8*)&As[pos * 8];
      }
      #pragma unroll
      for (int nt = 0; nt < 4; ++nt) {
        int n = wn + nt * 16 + ln;
        int pos = n * 8 + ((s * 4 + q) ^ (n & 7));
        b[nt] = *(const half8*)&Bs[pos * 8];
      }
      #pragma unroll
      for (int mt = 0; mt < 4; ++mt)
        #pragma unroll
        for (int nt = 0; nt < 4; ++nt)
          acc[mt][nt] = __builtin_amdgcn_mfma_f32_16x16x32_f16(
              a[mt], b[nt], acc[mt][nt], 0, 0, 0);
    }
    __syncthreads();
  }

  // acc = 2^11 * dot. d2 = xn + wn - 2*dot = xn + wn - acc * 2^-10.
  float wnv[4];
  #pragma unroll
  for (int nt = 0; nt < 4; ++nt) wnv[nt] = wnorm[n0 + wn + nt * 16 + ln];

  #pragma unroll
  for (int mt = 0; mt < 4; ++mt) {
    #pragma unroll
    for (int r = 0; r < 4; ++r) {
      int rowl = wm + mt * 16 + q * 4 + r;
      float xnv = xnorm[r0 + rowl];
      unsigned long long bp = ~0ull;
      #pragma unroll
      for (int nt = 0; nt < 4; ++nt) {
        float d2 = fmaxf(xnv + wnv[nt] - acc[mt][nt][r] * 0.0009765625f, 0.0f);
        unsigned col = (unsigned)(n0 + wn + nt * 16 + ln - lbase);
        unsigned long long p =
            ((unsigned long long)__float_as_uint(d2) << 32) | col;
        bp = (p < bp) ? p : bp;
      }
      #pragma unroll
      for (int off = 1; off < 16; off <<= 1) {
        unsigned long long o = __shfl_xor(bp, off);
        bp = (o < bp) ? o : bp;
      }
      if (ln == 0) red[w & 1][rowl] = bp;
    }
  }
  __syncthreads();
  if (t < 128) {
    unsigned long long a = red[0][t], b = red[1][t];
    unsigned long long m = (a < b) ? a : b;
    atomicMin(&best[level * 8192 + r0 + t], m);
  }
}

// One wave per (level,row): coords + exact fp32 quantization error.
__global__ __launch_bounds__(256) void finalize_kernel(
    const float* __restrict__ x, const float* __restrict__ w1,
    const float* __restrict__ w2, const float* __restrict__ w3,
    const unsigned long long* __restrict__ best, float* __restrict__ out) {
  int task = blockIdx.x * 4 + (threadIdx.x >> 6);
  int lane = threadIdx.x & 63;
  int level = task >> 13;
  int row = task & 8191;
  const float* w; unsigned side;
  if (level == 0)      { w = w1; side = 16; }
  else if (level == 1) { w = w2; side = 32; }
  else                 { w = w3; side = 64; }
  unsigned idx = (unsigned)(best[level * 8192 + row] & 0xFFFFFFFFull);
  float4 xv = *(const float4*)(x + (size_t)row * DIM + lane * 4);
  float4 wv = *(const float4*)(w + (size_t)idx * DIM + lane * 4);
  float dx = xv.x - wv.x, dy = xv.y - wv.y, dz = xv.z - wv.z, dw = xv.w - wv.w;
  float s = dx * dx + dy * dy + dz * dz + dw * dw;
  #pragma unroll
  for (int o = 32; o > 0; o >>= 1) s += __shfl_xor(s, o);
  if (lane == 0) {
    out[level * 16384 + row * 2 + 0] = (float)(idx / side);
    out[level * 16384 + row * 2 + 1] = (float)(idx % side);
    out[49152 + level * 8192 + row] = sqrtf(s);
  }
}

extern "C" void kernel_launch(void* const* d_in, const int* in_sizes, int n_in,
                              void* d_out, int out_size, void* d_ws, size_t ws_size,
                              hipStream_t stream) {
  const float* x  = (const float*)d_in[0];
  const float* w1 = (const float*)d_in[1];
  const float* w2 = (const float*)d_in[2];
  const float* w3 = (const float*)d_in[3];
  ushort* Xe = (ushort*)d_ws;
  ushort* We = (ushort*)((char*)d_ws + WS_WE_OFF);
  float* wnorm = (float*)((char*)d_ws + WS_WNORM_OFF);
  float* xnorm = (float*)((char*)d_ws + WS_XNORM_OFF);
  unsigned long long* best = (unsigned long long*)((char*)d_ws + WS_BEST_OFF);

  conv_kernel<<<3392, 256, 0, stream>>>(x, w1, w2, w3, Xe, We, wnorm, xnorm,
                                        best);
  gemm_kernel<<<dim3(42, 64), 256, 0, stream>>>(Xe, We, xnorm, wnorm, best);
  finalize_kernel<<<6144, 256, 0, stream>>>(x, w1, w2, w3, best, (float*)d_out);
}